// Round 21
// baseline (946.967 us; speedup 1.0000x reference)
//
#include <hip/hip_runtime.h>
#include <hip/hip_bf16.h>

#define K_DIM 256
__device__ __forceinline__ float lrelu_f(float x) { return x >= 0.f ? x : 0.2f * x; }

using bf16x8 = __attribute__((ext_vector_type(8))) short;
using f32x4 = __attribute__((ext_vector_type(4))) float;

__device__ __forceinline__ unsigned short f2bf(float x) {
  __hip_bfloat16 b = __float2bfloat16(x);
  return *(unsigned short*)&b;
}
__device__ __forceinline__ float bf2f(unsigned short u) {
  __hip_bfloat16 b = *(__hip_bfloat16*)&u;
  return __bfloat162float(b);
}

// frag-major index: tile(row>>4, k>>5), lane=(row&15)+((k>>3)&3)*16, elem=k&7.
// Same permutation for A and W frags -> cancels in the MFMA dot product.
__device__ __forceinline__ size_t frag_idx(int row, int k) {
  return (((size_t)(row >> 4) * 8 + (k >> 5)) * 64 + (row & 15) + (((k >> 3) & 3) << 4)) * 8 +
         (k & 7);
}

// ---------------- graph prep kernels ----------------

__global__ __launch_bounds__(256) void hist_kernel(const int* __restrict__ dst,
                                                   int* __restrict__ cnt, int E) {
  int e = blockIdx.x * 256 + threadIdx.x;
  if (e < E) atomicAdd(&cnt[dst[e]], 1);
}

__global__ __launch_bounds__(256) void dinv_kernel(const int* __restrict__ cnt,
                                                   float* __restrict__ dinv, int n) {
  int i = blockIdx.x * 256 + threadIdx.x;
  if (i < n) dinv[i] = rsqrtf((float)cnt[i] + 1.0f);
}

__global__ __launch_bounds__(256) void scan1_kernel(const int* __restrict__ cnt,
                                                    int* __restrict__ incl,
                                                    int* __restrict__ bsum, int n) {
  __shared__ int sm[256];
  int t = threadIdx.x;
  int i = blockIdx.x * 256 + t;
  int v = (i < n) ? cnt[i] : 0;
  sm[t] = v;
  __syncthreads();
  for (int off = 1; off < 256; off <<= 1) {
    int u = (t >= off) ? sm[t - off] : 0;
    __syncthreads();
    sm[t] += u;
    __syncthreads();
  }
  if (i < n) incl[i] = sm[t];
  if (t == 255) bsum[blockIdx.x] = sm[255];
}

__global__ __launch_bounds__(256) void scan2_kernel(const int* __restrict__ bsum,
                                                    int* __restrict__ boff, int nb) {
  __shared__ int sm[256];
  int t = threadIdx.x;
  int v = (t < nb) ? bsum[t] : 0;
  sm[t] = v;
  __syncthreads();
  for (int off = 1; off < 256; off <<= 1) {
    int u = (t >= off) ? sm[t - off] : 0;
    __syncthreads();
    sm[t] += u;
    __syncthreads();
  }
  boff[t] = sm[t] - v;  // exclusive
}

__global__ __launch_bounds__(256) void scan3_kernel(const int* __restrict__ incl,
                                                    const int* __restrict__ boff,
                                                    int* __restrict__ rowptr, int n) {
  int i = blockIdx.x * 256 + threadIdx.x;
  if (i < n) rowptr[i + 1] = incl[i] + boff[blockIdx.x];
  if (i == 0) rowptr[0] = 0;
}

__global__ __launch_bounds__(256) void scatter_kernel(const int* __restrict__ src,
                                                      const int* __restrict__ dst,
                                                      const int* __restrict__ rowptr,
                                                      int* __restrict__ cursor,
                                                      const float* __restrict__ dinv,
                                                      int* __restrict__ esrc,
                                                      float* __restrict__ ew, int E) {
  int e = blockIdx.x * 256 + threadIdx.x;
  if (e < E) {
    int d = dst[e];
    int p = rowptr[d] + atomicAdd(&cursor[d], 1);
    int s = src[e];
    esrc[p] = s;
    ew[p] = dinv[s];
  }
}

__global__ __launch_bounds__(256) void zerotail_kernel(unsigned short* __restrict__ a,
                                                       unsigned short* __restrict__ b,
                                                       size_t start, size_t count) {
  size_t i = (size_t)blockIdx.x * 256 + threadIdx.x;
  if (i < count) {
    a[start + i] = 0;
    b[start + i] = 0;
  }
}

// ---------------- split: y=(lrelu)(in); hi/lo bf16 split, FRAG-MAJOR output ----------------

template <bool LRELU>
__global__ __launch_bounds__(256) void split_kernel(const float* __restrict__ in,
                                                    unsigned short* __restrict__ hi,
                                                    unsigned short* __restrict__ lo,
                                                    int n4) {
  int i = blockIdx.x * 256 + threadIdx.x;
  if (i >= n4) return;
  int flat = i * 4;
  int row = flat >> 8;
  int k = flat & 255;
  float4 v = *(const float4*)(in + (size_t)flat);
  if (LRELU) {
    v.x = lrelu_f(v.x); v.y = lrelu_f(v.y); v.z = lrelu_f(v.z); v.w = lrelu_f(v.w);
  }
  ushort4 h, l;
  h.x = f2bf(v.x); l.x = f2bf(v.x - bf2f(h.x));
  h.y = f2bf(v.y); l.y = f2bf(v.y - bf2f(h.y));
  h.z = f2bf(v.z); l.z = f2bf(v.z - bf2f(h.z));
  h.w = f2bf(v.w); l.w = f2bf(v.w - bf2f(h.w));
  size_t d = frag_idx(row, k);  // k%4==0, 4 elems stay within the 8-elem frag
  *(ushort4*)(hi + d) = h;
  *(ushort4*)(lo + d) = l;
}

// ---------------- MFMA GEMM: H[M,NCOLS] = (Ah+Al)[M,256] @ (Wh+Wl)[NCOLS,256]^T ----------------
// Split-bf16 3-term (R17-verified: absmax unchanged vs fp32 path).
// Frag-major operands (R19: 80->53us). 512-thr 256Mx128N tile (R20: 53->45us).
// R21: REGISTER DOUBLE-BUFFER on the tk loop: issue tk+1's 16 coalesced frag
// loads before tk's 48 MFMAs -> ~600cy load latency hides under MFMA + the
// other wave. (R20 was latency-exposed: line-floor ~10us vs measured 45us.)
// launch_bounds(512,2) caps VGPR at 256 (acc 64 + 2x64 frag regs + addr).
// N-tile fastest in 1D grid (A panel L3-shared). C/D layout m89-verified.

template <int NCOLS>
__global__ __launch_bounds__(512, 2) void mfma_gemm_kernel(
    const unsigned short* __restrict__ Ah, const unsigned short* __restrict__ Al,
    const unsigned short* __restrict__ Wh, const unsigned short* __restrict__ Wl,
    float* __restrict__ H, int M) {
  constexpr int NY = NCOLS / 128;
  const int bx = blockIdx.x / NY;
  const int by = blockIdx.x % NY;
  const int tid = threadIdx.x;
  const int wv = tid >> 6;        // 0..7
  const int mg = wv & 3;          // M group
  const int ng = wv >> 2;         // N group
  const int lane = tid & 63;
  const int r = lane & 15;
  const int g = lane >> 4;
  const int bm = bx * 256 + mg * 64;
  const int bn = by * 128 + ng * 64;

  f32x4 acc[4][4];
#pragma unroll
  for (int i = 0; i < 4; ++i)
#pragma unroll
    for (int t = 0; t < 4; ++t) acc[i][t] = {0.f, 0.f, 0.f, 0.f};

  const int tm0 = bm >> 4;
  const int tn0 = bn >> 4;

  auto loadA = [&](int tk, bf16x8* AH, bf16x8* AL) {
#pragma unroll
    for (int i = 0; i < 4; ++i) {
      size_t base = (((size_t)(tm0 + i) * 8 + tk) * 64) * 8 + (size_t)lane * 8;
      AH[i] = *(const bf16x8*)(Ah + base);
      AL[i] = *(const bf16x8*)(Al + base);
    }
  };
  auto loadB = [&](int tk, bf16x8* BH, bf16x8* BL) {
#pragma unroll
    for (int t = 0; t < 4; ++t) {
      size_t base = (((size_t)(tn0 + t) * 8 + tk) * 64) * 8 + (size_t)lane * 8;
      BH[t] = *(const bf16x8*)(Wh + base);
      BL[t] = *(const bf16x8*)(Wl + base);
    }
  };

  bf16x8 cah[4], cal[4], cbh[4], cbl[4];
  bf16x8 nah[4], nal[4], nbh[4], nbl[4];
  loadA(0, cah, cal);
  loadB(0, cbh, cbl);

#pragma unroll
  for (int tk = 0; tk < 8; ++tk) {
    if (tk + 1 < 8) {
      loadA(tk + 1, nah, nal);
      loadB(tk + 1, nbh, nbl);
    }
#pragma unroll
    for (int i = 0; i < 4; ++i)
#pragma unroll
      for (int t = 0; t < 4; ++t) {
        acc[i][t] = __builtin_amdgcn_mfma_f32_16x16x32_bf16(cah[i], cbh[t], acc[i][t], 0, 0, 0);
        acc[i][t] = __builtin_amdgcn_mfma_f32_16x16x32_bf16(cah[i], cbl[t], acc[i][t], 0, 0, 0);
        acc[i][t] = __builtin_amdgcn_mfma_f32_16x16x32_bf16(cal[i], cbh[t], acc[i][t], 0, 0, 0);
      }
    if (tk + 1 < 8) {
#pragma unroll
      for (int i = 0; i < 4; ++i) {
        cah[i] = nah[i]; cal[i] = nal[i]; cbh[i] = nbh[i]; cbl[i] = nbl[i];
      }
    }
  }

#pragma unroll
  for (int i = 0; i < 4; ++i)
#pragma unroll
    for (int t = 0; t < 4; ++t) {
#pragma unroll
      for (int j = 0; j < 4; ++j) {
        int row = bm + i * 16 + g * 4 + j;
        if (row < M) H[(size_t)row * NCOLS + bn + t * 16 + r] = acc[i][t][j];
      }
    }
}

// ---------------- column-sliced aggregation, fused bias+lrelu+split epilogue ----------------
// out path (FUSE=false, layer 6): out[i] = dinv_i*agg + b  (fp32, row-major)
// fused path (FUSE=true): ah/al = bf16split(lrelu(dinv_i*agg + b)), FRAG-MAJOR.
// CW=COLS/8 col-group per XCD (R7 win). LINEAR node order (R12). Simple 4-way
// batch (R17: 8-deep's VGPR cost cut occupancy). R16/R19 model: at the
// line-service floor (~6.4M gather-line touches @ ~1 line/4cyc/CU) - structural.

template <int COLS, bool FUSE>
__global__ __launch_bounds__(256) void aggregate_kernel(
    const float* __restrict__ H, const int* __restrict__ rowptr,
    const int* __restrict__ esrc, const float* __restrict__ ew,
    const float* __restrict__ dinv, const float* __restrict__ bias,
    float* __restrict__ out, unsigned short* __restrict__ oh,
    unsigned short* __restrict__ ol, int n) {
  constexpr int CW = COLS / 8;
  constexpr int TPN = CW / 4;
  constexpr int NPB = 256 / TPN;
  const int g = blockIdx.x & 7;
  const int nb = blockIdx.x >> 3;
  const int t = threadIdx.x;
  const int ln = t / TPN;
  const int ct = t % TPN;
  const int node = nb * NPB + ln;
  if (node >= n) return;
  const int c0 = g * CW + ct * 4;
  const float* __restrict__ Hc = H + c0;
  const float di = dinv[node];

  float4 hs = *(const float4*)(Hc + (size_t)node * COLS);
  float a0 = di * hs.x, a1 = di * hs.y, a2 = di * hs.z, a3 = di * hs.w;

  const int e1 = rowptr[node + 1];
  int e = rowptr[node];
  for (; e + 4 <= e1; e += 4) {
    int s0 = esrc[e + 0], s1 = esrc[e + 1], s2 = esrc[e + 2], s3 = esrc[e + 3];
    float w0 = ew[e + 0], w1 = ew[e + 1], w2 = ew[e + 2], w3 = ew[e + 3];
    float4 h0 = *(const float4*)(Hc + (size_t)s0 * COLS);
    float4 h1 = *(const float4*)(Hc + (size_t)s1 * COLS);
    float4 h2 = *(const float4*)(Hc + (size_t)s2 * COLS);
    float4 h3 = *(const float4*)(Hc + (size_t)s3 * COLS);
    a0 = fmaf(w3, h3.x, fmaf(w2, h2.x, fmaf(w1, h1.x, fmaf(w0, h0.x, a0))));
    a1 = fmaf(w3, h3.y, fmaf(w2, h2.y, fmaf(w1, h1.y, fmaf(w0, h0.y, a1))));
    a2 = fmaf(w3, h3.z, fmaf(w2, h2.z, fmaf(w1, h1.z, fmaf(w0, h0.z, a2))));
    a3 = fmaf(w3, h3.w, fmaf(w2, h2.w, fmaf(w1, h1.w, fmaf(w0, h0.w, a3))));
  }
  for (; e < e1; ++e) {
    int s = esrc[e];
    float w = ew[e];
    float4 h = *(const float4*)(Hc + (size_t)s * COLS);
    a0 = fmaf(w, h.x, a0);
    a1 = fmaf(w, h.y, a1);
    a2 = fmaf(w, h.z, a2);
    a3 = fmaf(w, h.w, a3);
  }

  float4 b = *(const float4*)(bias + c0);
  float o0 = fmaf(di, a0, b.x);
  float o1 = fmaf(di, a1, b.y);
  float o2 = fmaf(di, a2, b.z);
  float o3 = fmaf(di, a3, b.w);

  if constexpr (FUSE) {
    o0 = lrelu_f(o0); o1 = lrelu_f(o1); o2 = lrelu_f(o2); o3 = lrelu_f(o3);
    ushort4 h, l;
    h.x = f2bf(o0); l.x = f2bf(o0 - bf2f(h.x));
    h.y = f2bf(o1); l.y = f2bf(o1 - bf2f(h.y));
    h.z = f2bf(o2); l.z = f2bf(o2 - bf2f(h.z));
    h.w = f2bf(o3); l.w = f2bf(o3 - bf2f(h.w));
    size_t d = frag_idx(node, c0);
    *(ushort4*)(oh + d) = h;
    *(ushort4*)(ol + d) = l;
  } else {
    float4 o;
    o.x = o0; o.y = o1; o.z = o2; o.w = o3;
    *(float4*)(out + (size_t)node * COLS + c0) = o;
  }
}

// ---------------- launch ----------------

extern "C" void kernel_launch(void* const* d_in, const int* in_sizes, int n_in,
                              void* d_out, int out_size, void* d_ws, size_t ws_size,
                              hipStream_t stream) {
  (void)n_in; (void)out_size; (void)ws_size;
  const float* x = (const float*)d_in[0];
  const int N = in_sizes[0] / 256;
  const int* ei = (const int*)d_in[1];
  const int E = in_sizes[1] / 2;
  const int* srcp = ei;
  const int* dstp = ei + E;
  const float* Wl6[6];
  const float* Bl[6];
  for (int i = 0; i < 6; i++) {
    Wl6[i] = (const float*)d_in[2 + 2 * i];
    Bl[i] = (const float*)d_in[3 + 2 * i];
  }
  float* out = (float*)d_out;

  char* p = (char*)d_ws;
  auto carve = [&](size_t bytes) {
    char* r = p;
    p += (bytes + 255) & ~(size_t)255;
    return (void*)r;
  };
  const int Mpad = (N + 255) & ~255;
  float* bufB = (float*)carve((size_t)N * 256 * 4);
  unsigned short* ah = (unsigned short*)carve((size_t)Mpad * 256 * 2);
  unsigned short* al = (unsigned short*)carve((size_t)Mpad * 256 * 2);
  unsigned short* wh = (unsigned short*)carve((size_t)256 * 256 * 2);
  unsigned short* wl = (unsigned short*)carve((size_t)256 * 256 * 2);
  int* cnt = (int*)carve((size_t)N * 4);
  float* dinv = (float*)carve((size_t)N * 4);
  int* incl = (int*)carve((size_t)N * 4);
  int* rowptr = (int*)carve((size_t)(N + 1) * 4);
  int* esrc = (int*)carve((size_t)E * 4);
  float* ew = (float*)carve((size_t)E * 4);
  int* bsum = (int*)carve(1024);
  int* boff = (int*)carve(1024);

  const int NB = (N + 255) / 256;

  hipMemsetAsync(cnt, 0, (size_t)N * 4, stream);
  hist_kernel<<<(E + 255) / 256, 256, 0, stream>>>(dstp, cnt, E);
  dinv_kernel<<<NB, 256, 0, stream>>>(cnt, dinv, N);
  scan1_kernel<<<NB, 256, 0, stream>>>(cnt, incl, bsum, N);
  scan2_kernel<<<1, 256, 0, stream>>>(bsum, boff, NB);
  scan3_kernel<<<NB, 256, 0, stream>>>(incl, boff, rowptr, N);
  hipMemsetAsync(cnt, 0, (size_t)N * 4, stream);
  scatter_kernel<<<(E + 255) / 256, 256, 0, stream>>>(srcp, dstp, rowptr, cnt, dinv,
                                                      esrc, ew, E);
  // zero pad-tile frags (rows N..Mpad): MFMA reads them; zeros contribute 0.
  {
    size_t start = (size_t)(N / 16) * 8 * 64 * 8;
    size_t total = (size_t)(Mpad / 16) * 8 * 64 * 8;
    size_t count = total - start;
    zerotail_kernel<<<(int)((count + 255) / 256), 256, 0, stream>>>(ah, al, start, count);
  }

  const int n4 = N * 64;  // float4 count for N x 256
  const int gsplit = (n4 + 255) / 256;
  const int gmfma256 = (Mpad / 256) * 2;  // 256x128 tiles, N fastest
  const int gmfma128 = (Mpad / 256) * 1;
  const int gagg256 = 8 * ((N + 31) / 32);
  const int gagg128 = 8 * ((N + 63) / 64);

  // layer 1: split x (no lrelu) frag-major, split W1, mfma, aggregate(fused)
  split_kernel<false><<<gsplit, 256, 0, stream>>>(x, ah, al, n4);
  split_kernel<false><<<(256 * 64 + 255) / 256, 256, 0, stream>>>(Wl6[0], wh, wl, 256 * 64);
  mfma_gemm_kernel<256><<<gmfma256, 512, 0, stream>>>(ah, al, wh, wl, bufB, N);
  aggregate_kernel<256, true><<<gagg256, 256, 0, stream>>>(bufB, rowptr, esrc, ew, dinv,
                                                           Bl[0], nullptr, ah, al, N);
  // layers 2..5
  for (int l = 1; l < 5; ++l) {
    split_kernel<false><<<(256 * 64 + 255) / 256, 256, 0, stream>>>(Wl6[l], wh, wl, 256 * 64);
    mfma_gemm_kernel<256><<<gmfma256, 512, 0, stream>>>(ah, al, wh, wl, bufB, N);
    aggregate_kernel<256, true><<<gagg256, 256, 0, stream>>>(bufB, rowptr, esrc, ew, dinv,
                                                             Bl[l], nullptr, ah, al, N);
  }
  // layer 6 (out dim 128): aggregate writes fp32 d_out, no lrelu
  split_kernel<false><<<(128 * 64 + 255) / 256, 256, 0, stream>>>(Wl6[5], wh, wl, 128 * 64);
  mfma_gemm_kernel<128><<<gmfma128, 512, 0, stream>>>(ah, al, wh, wl, bufB, N);
  aggregate_kernel<128, false><<<gagg128, 256, 0, stream>>>(bufB, rowptr, esrc, ew, dinv,
                                                            Bl[5], out, nullptr, nullptr, N);
}

// Round 22
// 903.736 us; speedup vs baseline: 1.0478x; 1.0478x over previous
//
#include <hip/hip_runtime.h>
#include <hip/hip_bf16.h>

#define K_DIM 256
__device__ __forceinline__ float lrelu_f(float x) { return x >= 0.f ? x : 0.2f * x; }

using bf16x8 = __attribute__((ext_vector_type(8))) short;
using f32x4 = __attribute__((ext_vector_type(4))) float;

__device__ __forceinline__ unsigned short f2bf(float x) {
  __hip_bfloat16 b = __float2bfloat16(x);
  return *(unsigned short*)&b;
}
__device__ __forceinline__ float bf2f(unsigned short u) {
  __hip_bfloat16 b = *(__hip_bfloat16*)&u;
  return __bfloat162float(b);
}

// frag-major index: tile(row>>4, k>>5), lane=(row&15)+((k>>3)&3)*16, elem=k&7.
// Same permutation for A and W frags -> cancels in the MFMA dot product.
__device__ __forceinline__ size_t frag_idx(int row, int k) {
  return (((size_t)(row >> 4) * 8 + (k >> 5)) * 64 + (row & 15) + (((k >> 3) & 3) << 4)) * 8 +
         (k & 7);
}

// ---------------- graph prep kernels ----------------

__global__ __launch_bounds__(256) void hist_kernel(const int* __restrict__ dst,
                                                   int* __restrict__ cnt, int E) {
  int e = blockIdx.x * 256 + threadIdx.x;
  if (e < E) atomicAdd(&cnt[dst[e]], 1);
}

__global__ __launch_bounds__(256) void dinv_kernel(const int* __restrict__ cnt,
                                                   float* __restrict__ dinv, int n) {
  int i = blockIdx.x * 256 + threadIdx.x;
  if (i < n) dinv[i] = rsqrtf((float)cnt[i] + 1.0f);
}

__global__ __launch_bounds__(256) void scan1_kernel(const int* __restrict__ cnt,
                                                    int* __restrict__ incl,
                                                    int* __restrict__ bsum, int n) {
  __shared__ int sm[256];
  int t = threadIdx.x;
  int i = blockIdx.x * 256 + t;
  int v = (i < n) ? cnt[i] : 0;
  sm[t] = v;
  __syncthreads();
  for (int off = 1; off < 256; off <<= 1) {
    int u = (t >= off) ? sm[t - off] : 0;
    __syncthreads();
    sm[t] += u;
    __syncthreads();
  }
  if (i < n) incl[i] = sm[t];
  if (t == 255) bsum[blockIdx.x] = sm[255];
}

__global__ __launch_bounds__(256) void scan2_kernel(const int* __restrict__ bsum,
                                                    int* __restrict__ boff, int nb) {
  __shared__ int sm[256];
  int t = threadIdx.x;
  int v = (t < nb) ? bsum[t] : 0;
  sm[t] = v;
  __syncthreads();
  for (int off = 1; off < 256; off <<= 1) {
    int u = (t >= off) ? sm[t - off] : 0;
    __syncthreads();
    sm[t] += u;
    __syncthreads();
  }
  boff[t] = sm[t] - v;  // exclusive
}

__global__ __launch_bounds__(256) void scan3_kernel(const int* __restrict__ incl,
                                                    const int* __restrict__ boff,
                                                    int* __restrict__ rowptr, int n) {
  int i = blockIdx.x * 256 + threadIdx.x;
  if (i < n) rowptr[i + 1] = incl[i] + boff[blockIdx.x];
  if (i == 0) rowptr[0] = 0;
}

__global__ __launch_bounds__(256) void scatter_kernel(const int* __restrict__ src,
                                                      const int* __restrict__ dst,
                                                      const int* __restrict__ rowptr,
                                                      int* __restrict__ cursor,
                                                      const float* __restrict__ dinv,
                                                      int* __restrict__ esrc,
                                                      float* __restrict__ ew, int E) {
  int e = blockIdx.x * 256 + threadIdx.x;
  if (e < E) {
    int d = dst[e];
    int p = rowptr[d] + atomicAdd(&cursor[d], 1);
    int s = src[e];
    esrc[p] = s;
    ew[p] = dinv[s];
  }
}

__global__ __launch_bounds__(256) void zerotail_kernel(unsigned short* __restrict__ a,
                                                       unsigned short* __restrict__ b,
                                                       size_t start, size_t count) {
  size_t i = (size_t)blockIdx.x * 256 + threadIdx.x;
  if (i < count) {
    a[start + i] = 0;
    b[start + i] = 0;
  }
}

// ---------------- split: y=(lrelu)(in); hi/lo bf16 split, FRAG-MAJOR output ----------------

template <bool LRELU>
__global__ __launch_bounds__(256) void split_kernel(const float* __restrict__ in,
                                                    unsigned short* __restrict__ hi,
                                                    unsigned short* __restrict__ lo,
                                                    int n4) {
  int i = blockIdx.x * 256 + threadIdx.x;
  if (i >= n4) return;
  int flat = i * 4;
  int row = flat >> 8;
  int k = flat & 255;
  float4 v = *(const float4*)(in + (size_t)flat);
  if (LRELU) {
    v.x = lrelu_f(v.x); v.y = lrelu_f(v.y); v.z = lrelu_f(v.z); v.w = lrelu_f(v.w);
  }
  ushort4 h, l;
  h.x = f2bf(v.x); l.x = f2bf(v.x - bf2f(h.x));
  h.y = f2bf(v.y); l.y = f2bf(v.y - bf2f(h.y));
  h.z = f2bf(v.z); l.z = f2bf(v.z - bf2f(h.z));
  h.w = f2bf(v.w); l.w = f2bf(v.w - bf2f(h.w));
  size_t d = frag_idx(row, k);  // k%4==0, 4 elems stay within the 8-elem frag
  *(ushort4*)(hi + d) = h;
  *(ushort4*)(lo + d) = l;
}

// ---------------- MFMA GEMM: H[M,NCOLS] = (Ah+Al)[M,256] @ (Wh+Wl)[NCOLS,256]^T ----------------
// Split-bf16 3-term (R17-verified: absmax unchanged vs fp32 path).
// Frag-major operands (R19 win: 80->53us). R20 (BEST): 512-thread block, tile
// 256Mx128N, 8 waves (4M x 2N), grid halved vs R19 -> device line-misses
// 500->300MB. R21 LESSON: register double-buffer of frag loads REGRESSED
// (45->54us) - prefetch VGPR state + copy chains cost more than latency saved;
// same failure family as R6's fp32 prefetch. Keep compiler-scheduled loads.
// N-tile fastest in 1D grid (A panel L3-shared). C/D layout m89-verified.

template <int NCOLS>
__global__ __launch_bounds__(512) void mfma_gemm_kernel(
    const unsigned short* __restrict__ Ah, const unsigned short* __restrict__ Al,
    const unsigned short* __restrict__ Wh, const unsigned short* __restrict__ Wl,
    float* __restrict__ H, int M) {
  constexpr int NY = NCOLS / 128;
  const int bx = blockIdx.x / NY;
  const int by = blockIdx.x % NY;
  const int tid = threadIdx.x;
  const int wv = tid >> 6;        // 0..7
  const int mg = wv & 3;          // M group
  const int ng = wv >> 2;         // N group
  const int lane = tid & 63;
  const int r = lane & 15;
  const int g = lane >> 4;
  const int bm = bx * 256 + mg * 64;
  const int bn = by * 128 + ng * 64;

  f32x4 acc[4][4];
#pragma unroll
  for (int i = 0; i < 4; ++i)
#pragma unroll
    for (int t = 0; t < 4; ++t) acc[i][t] = {0.f, 0.f, 0.f, 0.f};

  const int tm0 = bm >> 4;
  const int tn0 = bn >> 4;

  for (int tk = 0; tk < 8; ++tk) {
    bf16x8 ah[4], al[4], bh[4], bl[4];
#pragma unroll
    for (int i = 0; i < 4; ++i) {
      size_t base = (((size_t)(tm0 + i) * 8 + tk) * 64) * 8 + (size_t)lane * 8;
      ah[i] = *(const bf16x8*)(Ah + base);
      al[i] = *(const bf16x8*)(Al + base);
    }
#pragma unroll
    for (int t = 0; t < 4; ++t) {
      size_t base = (((size_t)(tn0 + t) * 8 + tk) * 64) * 8 + (size_t)lane * 8;
      bh[t] = *(const bf16x8*)(Wh + base);
      bl[t] = *(const bf16x8*)(Wl + base);
    }
#pragma unroll
    for (int i = 0; i < 4; ++i)
#pragma unroll
      for (int t = 0; t < 4; ++t) {
        acc[i][t] = __builtin_amdgcn_mfma_f32_16x16x32_bf16(ah[i], bh[t], acc[i][t], 0, 0, 0);
        acc[i][t] = __builtin_amdgcn_mfma_f32_16x16x32_bf16(ah[i], bl[t], acc[i][t], 0, 0, 0);
        acc[i][t] = __builtin_amdgcn_mfma_f32_16x16x32_bf16(al[i], bh[t], acc[i][t], 0, 0, 0);
      }
  }

#pragma unroll
  for (int i = 0; i < 4; ++i)
#pragma unroll
    for (int t = 0; t < 4; ++t) {
#pragma unroll
      for (int j = 0; j < 4; ++j) {
        int row = bm + i * 16 + g * 4 + j;
        if (row < M) H[(size_t)row * NCOLS + bn + t * 16 + r] = acc[i][t][j];
      }
    }
}

// ---------------- column-sliced aggregation, fused bias+lrelu+split epilogue ----------------
// out path (FUSE=false, layer 6): out[i] = dinv_i*agg + b  (fp32, row-major)
// fused path (FUSE=true): ah/al = bf16split(lrelu(dinv_i*agg + b)), FRAG-MAJOR.
// CW=COLS/8 col-group per XCD (R7 win). LINEAR node order (R12). Simple 4-way
// batch (R17: 8-deep's VGPR cost cut occupancy). R16/R19 model: at the
// line-service floor (~12.8M gather-line touches @ ~4cyc/line/CU) - structural;
// probed 6 ways (R4/R12/R13/R16 nulls), only col-slice-32 (R7) won.

template <int COLS, bool FUSE>
__global__ __launch_bounds__(256) void aggregate_kernel(
    const float* __restrict__ H, const int* __restrict__ rowptr,
    const int* __restrict__ esrc, const float* __restrict__ ew,
    const float* __restrict__ dinv, const float* __restrict__ bias,
    float* __restrict__ out, unsigned short* __restrict__ oh,
    unsigned short* __restrict__ ol, int n) {
  constexpr int CW = COLS / 8;
  constexpr int TPN = CW / 4;
  constexpr int NPB = 256 / TPN;
  const int g = blockIdx.x & 7;
  const int nb = blockIdx.x >> 3;
  const int t = threadIdx.x;
  const int ln = t / TPN;
  const int ct = t % TPN;
  const int node = nb * NPB + ln;
  if (node >= n) return;
  const int c0 = g * CW + ct * 4;
  const float* __restrict__ Hc = H + c0;
  const float di = dinv[node];

  float4 hs = *(const float4*)(Hc + (size_t)node * COLS);
  float a0 = di * hs.x, a1 = di * hs.y, a2 = di * hs.z, a3 = di * hs.w;

  const int e1 = rowptr[node + 1];
  int e = rowptr[node];
  for (; e + 4 <= e1; e += 4) {
    int s0 = esrc[e + 0], s1 = esrc[e + 1], s2 = esrc[e + 2], s3 = esrc[e + 3];
    float w0 = ew[e + 0], w1 = ew[e + 1], w2 = ew[e + 2], w3 = ew[e + 3];
    float4 h0 = *(const float4*)(Hc + (size_t)s0 * COLS);
    float4 h1 = *(const float4*)(Hc + (size_t)s1 * COLS);
    float4 h2 = *(const float4*)(Hc + (size_t)s2 * COLS);
    float4 h3 = *(const float4*)(Hc + (size_t)s3 * COLS);
    a0 = fmaf(w3, h3.x, fmaf(w2, h2.x, fmaf(w1, h1.x, fmaf(w0, h0.x, a0))));
    a1 = fmaf(w3, h3.y, fmaf(w2, h2.y, fmaf(w1, h1.y, fmaf(w0, h0.y, a1))));
    a2 = fmaf(w3, h3.z, fmaf(w2, h2.z, fmaf(w1, h1.z, fmaf(w0, h0.z, a2))));
    a3 = fmaf(w3, h3.w, fmaf(w2, h2.w, fmaf(w1, h1.w, fmaf(w0, h0.w, a3))));
  }
  for (; e < e1; ++e) {
    int s = esrc[e];
    float w = ew[e];
    float4 h = *(const float4*)(Hc + (size_t)s * COLS);
    a0 = fmaf(w, h.x, a0);
    a1 = fmaf(w, h.y, a1);
    a2 = fmaf(w, h.z, a2);
    a3 = fmaf(w, h.w, a3);
  }

  float4 b = *(const float4*)(bias + c0);
  float o0 = fmaf(di, a0, b.x);
  float o1 = fmaf(di, a1, b.y);
  float o2 = fmaf(di, a2, b.z);
  float o3 = fmaf(di, a3, b.w);

  if constexpr (FUSE) {
    o0 = lrelu_f(o0); o1 = lrelu_f(o1); o2 = lrelu_f(o2); o3 = lrelu_f(o3);
    ushort4 h, l;
    h.x = f2bf(o0); l.x = f2bf(o0 - bf2f(h.x));
    h.y = f2bf(o1); l.y = f2bf(o1 - bf2f(h.y));
    h.z = f2bf(o2); l.z = f2bf(o2 - bf2f(h.z));
    h.w = f2bf(o3); l.w = f2bf(o3 - bf2f(h.w));
    size_t d = frag_idx(node, c0);
    *(ushort4*)(oh + d) = h;
    *(ushort4*)(ol + d) = l;
  } else {
    float4 o;
    o.x = o0; o.y = o1; o.z = o2; o.w = o3;
    *(float4*)(out + (size_t)node * COLS + c0) = o;
  }
}

// ---------------- launch ----------------

extern "C" void kernel_launch(void* const* d_in, const int* in_sizes, int n_in,
                              void* d_out, int out_size, void* d_ws, size_t ws_size,
                              hipStream_t stream) {
  (void)n_in; (void)out_size; (void)ws_size;
  const float* x = (const float*)d_in[0];
  const int N = in_sizes[0] / 256;
  const int* ei = (const int*)d_in[1];
  const int E = in_sizes[1] / 2;
  const int* srcp = ei;
  const int* dstp = ei + E;
  const float* Wl6[6];
  const float* Bl[6];
  for (int i = 0; i < 6; i++) {
    Wl6[i] = (const float*)d_in[2 + 2 * i];
    Bl[i] = (const float*)d_in[3 + 2 * i];
  }
  float* out = (float*)d_out;

  char* p = (char*)d_ws;
  auto carve = [&](size_t bytes) {
    char* r = p;
    p += (bytes + 255) & ~(size_t)255;
    return (void*)r;
  };
  const int Mpad = (N + 255) & ~255;
  float* bufB = (float*)carve((size_t)N * 256 * 4);
  unsigned short* ah = (unsigned short*)carve((size_t)Mpad * 256 * 2);
  unsigned short* al = (unsigned short*)carve((size_t)Mpad * 256 * 2);
  unsigned short* wh = (unsigned short*)carve((size_t)256 * 256 * 2);
  unsigned short* wl = (unsigned short*)carve((size_t)256 * 256 * 2);
  int* cnt = (int*)carve((size_t)N * 4);
  float* dinv = (float*)carve((size_t)N * 4);
  int* incl = (int*)carve((size_t)N * 4);
  int* rowptr = (int*)carve((size_t)(N + 1) * 4);
  int* esrc = (int*)carve((size_t)E * 4);
  float* ew = (float*)carve((size_t)E * 4);
  int* bsum = (int*)carve(1024);
  int* boff = (int*)carve(1024);

  const int NB = (N + 255) / 256;

  hipMemsetAsync(cnt, 0, (size_t)N * 4, stream);
  hist_kernel<<<(E + 255) / 256, 256, 0, stream>>>(dstp, cnt, E);
  dinv_kernel<<<NB, 256, 0, stream>>>(cnt, dinv, N);
  scan1_kernel<<<NB, 256, 0, stream>>>(cnt, incl, bsum, N);
  scan2_kernel<<<1, 256, 0, stream>>>(bsum, boff, NB);
  scan3_kernel<<<NB, 256, 0, stream>>>(incl, boff, rowptr, N);
  hipMemsetAsync(cnt, 0, (size_t)N * 4, stream);
  scatter_kernel<<<(E + 255) / 256, 256, 0, stream>>>(srcp, dstp, rowptr, cnt, dinv,
                                                      esrc, ew, E);
  // zero pad-tile frags (rows N..Mpad): MFMA reads them; zeros contribute 0.
  {
    size_t start = (size_t)(N / 16) * 8 * 64 * 8;
    size_t total = (size_t)(Mpad / 16) * 8 * 64 * 8;
    size_t count = total - start;
    zerotail_kernel<<<(int)((count + 255) / 256), 256, 0, stream>>>(ah, al, start, count);
  }

  const int n4 = N * 64;  // float4 count for N x 256
  const int gsplit = (n4 + 255) / 256;
  const int gmfma256 = (Mpad / 256) * 2;  // 256x128 tiles, N fastest
  const int gmfma128 = (Mpad / 256) * 1;
  const int gagg256 = 8 * ((N + 31) / 32);
  const int gagg128 = 8 * ((N + 63) / 64);

  // layer 1: split x (no lrelu) frag-major, split W1, mfma, aggregate(fused)
  split_kernel<false><<<gsplit, 256, 0, stream>>>(x, ah, al, n4);
  split_kernel<false><<<(256 * 64 + 255) / 256, 256, 0, stream>>>(Wl6[0], wh, wl, 256 * 64);
  mfma_gemm_kernel<256><<<gmfma256, 512, 0, stream>>>(ah, al, wh, wl, bufB, N);
  aggregate_kernel<256, true><<<gagg256, 256, 0, stream>>>(bufB, rowptr, esrc, ew, dinv,
                                                           Bl[0], nullptr, ah, al, N);
  // layers 2..5
  for (int l = 1; l < 5; ++l) {
    split_kernel<false><<<(256 * 64 + 255) / 256, 256, 0, stream>>>(Wl6[l], wh, wl, 256 * 64);
    mfma_gemm_kernel<256><<<gmfma256, 512, 0, stream>>>(ah, al, wh, wl, bufB, N);
    aggregate_kernel<256, true><<<gagg256, 256, 0, stream>>>(bufB, rowptr, esrc, ew, dinv,
                                                             Bl[l], nullptr, ah, al, N);
  }
  // layer 6 (out dim 128): aggregate writes fp32 d_out, no lrelu
  split_kernel<false><<<(128 * 64 + 255) / 256, 256, 0, stream>>>(Wl6[5], wh, wl, 128 * 64);
  mfma_gemm_kernel<128><<<gmfma128, 512, 0, stream>>>(ah, al, wh, wl, bufB, N);
  aggregate_kernel<128, false><<<gagg128, 256, 0, stream>>>(bufB, rowptr, esrc, ew, dinv,
                                                            Bl[5], out, nullptr, nullptr, N);
}